// Round 6
// baseline (312.957 us; speedup 1.0000x reference)
//
#include <hip/hip_runtime.h>
#include <hip/hip_bf16.h>

// GraphTransformerLayer: B=8, N=1024, E=256, H=8, D=32, C=4 (all fp32 in/out)
#define BATCH 8
#define SEQ   1024
#define EMB   256
#define NH    8
#define HD    32
#define QSCALE 0.2550030053f   // log2(e)/sqrt(32), folded into Wq/bq

typedef __attribute__((ext_vector_type(8))) short short8;
typedef __attribute__((ext_vector_type(4))) float floatx4;

__device__ __forceinline__ ushort f2bf(float f) {
    __hip_bfloat16 h = __float2bfloat16(f);
    return *reinterpret_cast<ushort*>(&h);
}
__device__ __forceinline__ unsigned int pack2bf(float lo, float hi) {
    return (unsigned int)f2bf(lo) | ((unsigned int)f2bf(hi) << 16);
}

// async 16B/lane global->LDS DMA (wave-uniform LDS base + lane*16)
__device__ __forceinline__ void gload_lds16(const float4* g, float4* l) {
    __builtin_amdgcn_global_load_lds(
        (const __attribute__((address_space(1))) unsigned int*)g,
        (__attribute__((address_space(3))) unsigned int*)l, 16, 0, 0);
}

// ---------------------------------------------------------------------------
// Kernel 0: prep — transpose Wq,Wk,Wv,Wo (fp32 [K][N]) to bf16 [N][K].
// Wq pre-scaled by log2(e)/sqrt(32). 256 blocks: matrix = blk/64, 8x8 tiles.
// ---------------------------------------------------------------------------
__global__ __launch_bounds__(256) void prep_kernel(
    const float* __restrict__ Wq, const float* __restrict__ Wk,
    const float* __restrict__ Wv, const float* __restrict__ Wo,
    ushort* __restrict__ Wqt, ushort* __restrict__ Wkt,
    ushort* __restrict__ Wvt, ushort* __restrict__ Wot)
{
    __shared__ float tilebuf[32][33];
    const int blk = blockIdx.x;
    const int mat = blk >> 6, tile = blk & 63;
    const int ti = tile >> 3, tj = tile & 7;
    const float* W = (mat == 0) ? Wq : (mat == 1) ? Wk : (mat == 2) ? Wv : Wo;
    ushort* Wt = (mat == 0) ? Wqt : (mat == 1) ? Wkt : (mat == 2) ? Wvt : Wot;
    const float scale = (mat == 0) ? QSCALE : 1.0f;

    const int tx = threadIdx.x & 31, ty = threadIdx.x >> 5;
    #pragma unroll
    for (int p = 0; p < 4; ++p)
        tilebuf[ty + p * 8][tx] = W[(size_t)(ti * 32 + ty + p * 8) * EMB + tj * 32 + tx];
    __syncthreads();
    #pragma unroll
    for (int p = 0; p < 4; ++p)
        Wt[(size_t)(tj * 32 + ty + p * 8) * EMB + ti * 32 + tx] =
            f2bf(tilebuf[tx][ty + p * 8] * scale);
}

// ---------------------------------------------------------------------------
// Kernel 1: QKV projection as MFMA GEMM (unchanged — correct since r4).
// Q,K -> [B,H,N,D] bf16; V -> [B,H,D,N] bf16.
// ---------------------------------------------------------------------------
__global__ __launch_bounds__(256) void qkv_gemm(
    const float* __restrict__ x,
    const ushort* __restrict__ Wqt, const ushort* __restrict__ Wkt,
    const ushort* __restrict__ Wvt,
    const float* __restrict__ bq, const float* __restrict__ bk,
    const float* __restrict__ bv,
    ushort* __restrict__ Qb, ushort* __restrict__ Kb, ushort* __restrict__ Vt)
{
    const int mat = blockIdx.y;
    const ushort* __restrict__ Wt = (mat == 0) ? Wqt : (mat == 1) ? Wkt : Wvt;
    const float* __restrict__ bias = (mat == 0) ? bq : (mat == 1) ? bk : bv;
    const float bscale = (mat == 0) ? QSCALE : 1.0f;

    const int w = threadIdx.x >> 6, lane = threadIdx.x & 63;
    const int quad = lane >> 4, l16 = lane & 15;
    const int row0 = blockIdx.x * 64 + w * 16;

    floatx4 acc[16];
    #pragma unroll
    for (int i = 0; i < 16; ++i) acc[i] = (floatx4){0.f, 0.f, 0.f, 0.f};

    const float* __restrict__ xrow = x + (size_t)(row0 + l16) * EMB + quad * 8;

    #pragma unroll
    for (int ks = 0; ks < 8; ++ks) {
        const float4 xa0 = *(const float4*)(xrow + ks * 32);
        const float4 xa1 = *(const float4*)(xrow + ks * 32 + 4);
        ushort au[8] = {f2bf(xa0.x), f2bf(xa0.y), f2bf(xa0.z), f2bf(xa0.w),
                        f2bf(xa1.x), f2bf(xa1.y), f2bf(xa1.z), f2bf(xa1.w)};
        const short8 a = *(const short8*)au;
        #pragma unroll
        for (int i = 0; i < 16; ++i) {
            const short8 bf = *(const short8*)(Wt + (size_t)(i * 16 + l16) * EMB + ks * 32 + quad * 8);
            acc[i] = __builtin_amdgcn_mfma_f32_16x16x32_bf16(a, bf, acc[i], 0, 0, 0);
        }
    }

    const int gr0 = row0 + quad * 4;
    if (mat < 2) {
        ushort* __restrict__ dst = (mat == 0) ? Qb : Kb;
        #pragma unroll
        for (int i = 0; i < 16; ++i) {
            const int c = i * 16 + l16, h = c >> 5, d = c & (HD - 1);
            const float bb = bias[c] * bscale;
            #pragma unroll
            for (int r = 0; r < 4; ++r) {
                const int gr = gr0 + r, b = gr >> 10, n = gr & (SEQ - 1);
                dst[((size_t)(b * NH + h) * SEQ + n) * HD + d] = f2bf(acc[i][r] + bb);
            }
        }
    } else {
        const int b = gr0 >> 10, n0 = gr0 & (SEQ - 1);
        #pragma unroll
        for (int i = 0; i < 16; ++i) {
            const int c = i * 16 + l16, h = c >> 5, d = c & (HD - 1);
            const float bb = bias[c];
            ushort4 t4;
            t4.x = f2bf(acc[i][0] + bb); t4.y = f2bf(acc[i][1] + bb);
            t4.z = f2bf(acc[i][2] + bb); t4.w = f2bf(acc[i][3] + bb);
            *(ushort4*)(Vt + ((size_t)(b * NH + h) * HD + d) * SEQ + n0) = t4;
        }
    }
}

// ---------------------------------------------------------------------------
// Kernel 2: attention, TRANSPOSED formulation. S^T = K·Q^T (swap MFMA
// operands) so P^T sits in C-layout [key rows, q cols]; the PV product
// ctx^T = V^T·P^T needs P^T as B-operand, reached by a pure in-register
// cross-quad shuffle (no LDS roundtrip, no lgkmcnt(0) barrier).
// adj tile staged once/block via double-buffered global_load_lds DMA.
// LDS = 33.3 KB -> 4 blocks/CU; grid 64x8x2 = 1024 = exactly 4/CU (no tail).
// ---------------------------------------------------------------------------
__global__ __launch_bounds__(512, 8) void attn_kernel(
    const ushort* __restrict__ Qb, const ushort* __restrict__ Kb,
    const ushort* __restrict__ Vt, const float* __restrict__ adj,
    const float* __restrict__ Wa, const float* __restrict__ ba,
    float* __restrict__ cp, float* __restrict__ lsum)
{
    __shared__ float4 Atile[2][16][65];      // 33280 B, +1 float4 row pad
    const int tid = threadIdx.x, h = tid >> 6, lane = tid & 63;
    const int quad = lane >> 4, l16 = lane & 15;
    const int q0 = blockIdx.x * 16, b = blockIdx.y, z = blockIdx.z;
    const int bh = b * NH + h;
    const int kz = z * 512;

    const float LOG2E = 1.4426950408889634f;
    const float wa0 = Wa[0 * NH + h] * LOG2E, wa1 = Wa[1 * NH + h] * LOG2E;
    const float wa2 = Wa[2 * NH + h] * LOG2E, wa3 = Wa[3 * NH + h] * LOG2E;
    const float bah = ba[h] * LOG2E;

    // Q as B-operand: B[n=q=l16][k=d=quad*8+j]  (same frag as before)
    const short8 aq = *(const short8*)(Qb + ((size_t)bh * SEQ + q0 + l16) * HD + quad * 8);

    floatx4 o0 = {0.f, 0.f, 0.f, 0.f}, o1 = {0.f, 0.f, 0.f, 0.f};
    float lacc = 0.f;

    const float4* __restrict__ adjb = (const float4*)adj + (size_t)b * SEQ * SEQ;
    const float4* __restrict__ asrc0 = adjb + (size_t)(q0 + 2 * h)     * SEQ + kz + lane;
    const float4* __restrict__ asrc1 = adjb + (size_t)(q0 + 2 * h + 1) * SEQ + kz + lane;

    const ushort* __restrict__ Kbase = Kb + (size_t)bh * SEQ * HD + (size_t)l16 * HD + quad * 8;
    const ushort* __restrict__ Vb0 = Vt + ((size_t)bh * HD + l16) * SEQ + quad * 8;
    const ushort* __restrict__ Vb1 = Vt + ((size_t)bh * HD + 16 + l16) * SEQ + quad * 8;

    // shuffle sources for the P^T C-layout -> B-layout redistribution:
    // dest quad qd pulls from source quads {2*(qd&1), 2*(qd&1)+1}, same l16;
    // low dest quads (qd<2) take the first-16-keys dwords, high take +16.
    const int laneA = l16 | ((quad & 1) << 5);   // quad 0 or 2
    const int laneB = laneA + 16;                // quad 1 or 3
    const bool lowsel = quad < 2;

    gload_lds16(asrc0, &Atile[0][2 * h][0]);
    gload_lds16(asrc1, &Atile[0][2 * h + 1][0]);
    __syncthreads();   // vmcnt(0) drain -> tile 0 resident

    for (int it = 0; it < 8; ++it) {
        const int cur = it & 1;
        if (it < 7) {
            gload_lds16(asrc0 + (it + 1) * 64, &Atile[cur ^ 1][2 * h][0]);
            gload_lds16(asrc1 + (it + 1) * 64, &Atile[cur ^ 1][2 * h + 1][0]);
        }
        const int key0 = kz + it * 64;

        #pragma unroll
        for (int c = 0; c < 2; ++c) {
            const int kc = key0 + c * 32;
            // K as A-operand: A[m=key=l16][k=d]
            const short8 ka = *(const short8*)(Kbase + (size_t)kc * HD);
            const short8 kb = *(const short8*)(Kbase + (size_t)(kc + 16) * HD);
            const floatx4 zz = {0.f, 0.f, 0.f, 0.f};
            floatx4 sA = __builtin_amdgcn_mfma_f32_16x16x32_bf16(ka, aq, zz, 0, 0, 0);
            floatx4 sB = __builtin_amdgcn_mfma_f32_16x16x32_bf16(kb, aq, zz, 0, 0, 0);
            // sA[r] = S^T[key=kc+4*quad+r][q=l16], sB: keys +16

            float pA[4], pB[4];
            #pragma unroll
            for (int r = 0; r < 4; ++r) {
                const int col = c * 32 + 4 * quad + r;      // key rel. tile
                const float4 a0 = Atile[cur][l16][col];
                const float4 a1 = Atile[cur][l16][col + 16];
                const float b0 = fmaf(a0.x, wa0, fmaf(a0.y, wa1, fmaf(a0.z, wa2, fmaf(a0.w, wa3, bah))));
                const float b1 = fmaf(a1.x, wa0, fmaf(a1.y, wa1, fmaf(a1.z, wa2, fmaf(a1.w, wa3, bah))));
                pA[r] = exp2f(sA[r] + b0);
                pB[r] = exp2f(sB[r] + b1);
                lacc += pA[r] + pB[r];
            }
            // pack to bf16 pairs: d0,d1 = keys [4sq..4sq+3]; d2,d3 = +16
            const unsigned int d0 = pack2bf(pA[0], pA[1]);
            const unsigned int d1 = pack2bf(pA[2], pA[3]);
            const unsigned int d2 = pack2bf(pB[0], pB[1]);
            const unsigned int d3 = pack2bf(pB[2], pB[3]);
            // redistribute: dest lane (qd,l16) collects keys qd*8..qd*8+7
            const int t0A = __shfl((int)d0, laneA, 64);
            const int t2A = __shfl((int)d2, laneA, 64);
            const int t1A = __shfl((int)d1, laneA, 64);
            const int t3A = __shfl((int)d3, laneA, 64);
            const int t0B = __shfl((int)d0, laneB, 64);
            const int t2B = __shfl((int)d2, laneB, 64);
            const int t1B = __shfl((int)d1, laneB, 64);
            const int t3B = __shfl((int)d3, laneB, 64);
            int4 rr;
            rr.x = lowsel ? t0A : t2A;
            rr.y = lowsel ? t1A : t3A;
            rr.z = lowsel ? t0B : t2B;
            rr.w = lowsel ? t1B : t3B;
            const short8 bp = __builtin_bit_cast(short8, rr);   // B[n=q][k=key]

            // V^T as A-operand: A[m=d][k=key]
            const short8 va0 = *(const short8*)(Vb0 + kc);
            const short8 va1 = *(const short8*)(Vb1 + kc);
            o0 = __builtin_amdgcn_mfma_f32_16x16x32_bf16(va0, bp, o0, 0, 0, 0);
            o1 = __builtin_amdgcn_mfma_f32_16x16x32_bf16(va1, bp, o1, 0, 0, 0);
        }
        __syncthreads();   // all waves done with Atile[cur]; next DMA arrived
    }

    // l per q=l16: sum across the 4 quads
    lacc += __shfl_xor(lacc, 16, 64);
    lacc += __shfl_xor(lacc, 32, 64);

    float* __restrict__ cpz = cp + (size_t)z * BATCH * SEQ * EMB;
    float* __restrict__ lsz = lsum + (size_t)z * BATCH * SEQ * NH;
    const size_t grow = (size_t)b * SEQ + q0 + l16;
    // o0[r] = ctx^T[d=quad*4+r][q=l16] (d 0-15), o1: d 16-31
    #pragma unroll
    for (int r = 0; r < 4; ++r) {
        cpz[grow * EMB + h * HD + quad * 4 + r]      = o0[r];
        cpz[grow * EMB + h * HD + 16 + quad * 4 + r] = o1[r];
    }
    if (lane < 16)
        lsz[((size_t)b * SEQ + q0 + lane) * NH + h] = lacc;
}

// ---------------------------------------------------------------------------
// Kernel 3: outproj as MFMA GEMM (unchanged — combine splits, normalize,
// + bo + x residual).
// ---------------------------------------------------------------------------
__global__ __launch_bounds__(256) void outproj_gemm(
    const float* __restrict__ cp, const float* __restrict__ lsum,
    const ushort* __restrict__ Wot, const float* __restrict__ bo,
    const float* __restrict__ x, float* __restrict__ out)
{
    const int w = threadIdx.x >> 6, lane = threadIdx.x & 63;
    const int quad = lane >> 4, l16 = lane & 15;
    const int row0 = blockIdx.x * 64 + w * 16;
    const int arow = row0 + l16;
    const float* __restrict__ cp1 = cp + (size_t)BATCH * SEQ * EMB;
    const float* __restrict__ l1  = lsum + (size_t)BATCH * SEQ * NH;

    floatx4 acc[16];
    #pragma unroll
    for (int i = 0; i < 16; ++i) acc[i] = (floatx4){0.f, 0.f, 0.f, 0.f};

    #pragma unroll
    for (int ks = 0; ks < 8; ++ks) {
        const float invl = 1.0f / (lsum[(size_t)arow * NH + ks] + l1[(size_t)arow * NH + ks]);
        const size_t cb = (size_t)arow * EMB + ks * 32 + quad * 8;
        const float4 c00 = *(const float4*)(cp + cb);
        const float4 c01 = *(const float4*)(cp + cb + 4);
        const float4 c10 = *(const float4*)(cp1 + cb);
        const float4 c11 = *(const float4*)(cp1 + cb + 4);
        ushort au[8] = {
            f2bf((c00.x + c10.x) * invl), f2bf((c00.y + c10.y) * invl),
            f2bf((c00.z + c10.z) * invl), f2bf((c00.w + c10.w) * invl),
            f2bf((c01.x + c11.x) * invl), f2bf((c01.y + c11.y) * invl),
            f2bf((c01.z + c11.z) * invl), f2bf((c01.w + c11.w) * invl)};
        const short8 a = *(const short8*)au;
        #pragma unroll
        for (int i = 0; i < 16; ++i) {
            const short8 bfr = *(const short8*)(Wot + (size_t)(i * 16 + l16) * EMB + ks * 32 + quad * 8);
            acc[i] = __builtin_amdgcn_mfma_f32_16x16x32_bf16(a, bfr, acc[i], 0, 0, 0);
        }
    }

    const int gr0 = row0 + quad * 4;
    #pragma unroll
    for (int i = 0; i < 16; ++i) {
        const int c = i * 16 + l16;
        const float bov = bo[c];
        #pragma unroll
        for (int r = 0; r < 4; ++r) {
            const size_t idx = (size_t)(gr0 + r) * EMB + c;
            out[idx] = acc[i][r] + bov + x[idx];
        }
    }
}

extern "C" void kernel_launch(void* const* d_in, const int* in_sizes, int n_in,
                              void* d_out, int out_size, void* d_ws, size_t ws_size,
                              hipStream_t stream) {
    const float* x   = (const float*)d_in[0];
    const float* adj = (const float*)d_in[1];
    const float* Wq  = (const float*)d_in[2];
    const float* bq  = (const float*)d_in[3];
    const float* Wk  = (const float*)d_in[4];
    const float* bk  = (const float*)d_in[5];
    const float* Wv  = (const float*)d_in[6];
    const float* bv  = (const float*)d_in[7];
    const float* Wo  = (const float*)d_in[8];
    const float* bo  = (const float*)d_in[9];
    const float* Wa  = (const float*)d_in[10];
    const float* ba  = (const float*)d_in[11];

    const size_t per = (size_t)BATCH * NH * SEQ * HD;   // 2,097,152
    ushort* Qb  = (ushort*)d_ws;
    ushort* Kb  = Qb + per;
    ushort* Vt  = Kb + per;
    ushort* Wqt = Vt + per;
    ushort* Wkt = Wqt + EMB * EMB;
    ushort* Wvt = Wkt + EMB * EMB;
    ushort* Wot = Wvt + EMB * EMB;
    float*  cp  = (float*)(Wot + EMB * EMB);            // 2 x 8 MB fp32
    float*  ls  = cp + 2 * (size_t)BATCH * SEQ * EMB;   // 2 x 256 KB

    prep_kernel<<<256, 256, 0, stream>>>(Wq, Wk, Wv, Wo, Wqt, Wkt, Wvt, Wot);
    qkv_gemm<<<dim3(BATCH * SEQ / 64, 3), 256, 0, stream>>>(
        x, Wqt, Wkt, Wvt, bq, bk, bv, Qb, Kb, Vt);
    attn_kernel<<<dim3(SEQ / 16, BATCH, 2), 512, 0, stream>>>(
        Qb, Kb, Vt, adj, Wa, ba, cp, ls);
    outproj_gemm<<<BATCH * SEQ / 64, 256, 0, stream>>>(
        cp, ls, Wot, bo, x, (float*)d_out);
}

// Round 7
// 306.244 us; speedup vs baseline: 1.0219x; 1.0219x over previous
//
#include <hip/hip_runtime.h>
#include <hip/hip_bf16.h>

// GraphTransformerLayer: B=8, N=1024, E=256, H=8, D=32, C=4 (all fp32 in/out)
#define BATCH 8
#define SEQ   1024
#define EMB   256
#define NH    8
#define HD    32
#define QSCALE 0.2550030053f   // log2(e)/sqrt(32), folded into Wq/bq

typedef __attribute__((ext_vector_type(8))) short short8;
typedef __attribute__((ext_vector_type(4))) float floatx4;

__device__ __forceinline__ ushort f2bf(float f) {
    __hip_bfloat16 h = __float2bfloat16(f);
    return *reinterpret_cast<ushort*>(&h);
}
// truncating bf16x2 pack: high halves of two f32 in one v_perm_b32
__device__ __forceinline__ unsigned int packtrunc(float lo, float hi) {
    return __builtin_amdgcn_perm(__builtin_bit_cast(unsigned int, hi),
                                 __builtin_bit_cast(unsigned int, lo),
                                 0x07060302u);
}

// async 16B/lane global->LDS DMA (wave-uniform LDS base + lane*16)
__device__ __forceinline__ void gload_lds16(const float4* g, float4* l) {
    __builtin_amdgcn_global_load_lds(
        (const __attribute__((address_space(1))) unsigned int*)g,
        (__attribute__((address_space(3))) unsigned int*)l, 16, 0, 0);
}

// ---------------------------------------------------------------------------
// Kernel 0: prep — transpose Wq,Wk,Wv,Wo (fp32 [K][N]) to bf16 [N][K].
// Wq pre-scaled by log2(e)/sqrt(32).
// ---------------------------------------------------------------------------
__global__ __launch_bounds__(256) void prep_kernel(
    const float* __restrict__ Wq, const float* __restrict__ Wk,
    const float* __restrict__ Wv, const float* __restrict__ Wo,
    ushort* __restrict__ Wqt, ushort* __restrict__ Wkt,
    ushort* __restrict__ Wvt, ushort* __restrict__ Wot)
{
    __shared__ float tilebuf[32][33];
    const int blk = blockIdx.x;
    const int mat = blk >> 6, tile = blk & 63;
    const int ti = tile >> 3, tj = tile & 7;
    const float* W = (mat == 0) ? Wq : (mat == 1) ? Wk : (mat == 2) ? Wv : Wo;
    ushort* Wt = (mat == 0) ? Wqt : (mat == 1) ? Wkt : (mat == 2) ? Wvt : Wot;
    const float scale = (mat == 0) ? QSCALE : 1.0f;

    const int tx = threadIdx.x & 31, ty = threadIdx.x >> 5;
    #pragma unroll
    for (int p = 0; p < 4; ++p)
        tilebuf[ty + p * 8][tx] = W[(size_t)(ti * 32 + ty + p * 8) * EMB + tj * 32 + tx];
    __syncthreads();
    #pragma unroll
    for (int p = 0; p < 4; ++p)
        Wt[(size_t)(tj * 32 + ty + p * 8) * EMB + ti * 32 + tx] =
            f2bf(tilebuf[tx][ty + p * 8] * scale);
}

// ---------------------------------------------------------------------------
// Kernel 1: QKV projection as MFMA GEMM (unchanged — correct since r4).
// Q,K -> [B,H,N,D] bf16; V -> [B,H,D,N] bf16.
// ---------------------------------------------------------------------------
__global__ __launch_bounds__(256) void qkv_gemm(
    const float* __restrict__ x,
    const ushort* __restrict__ Wqt, const ushort* __restrict__ Wkt,
    const ushort* __restrict__ Wvt,
    const float* __restrict__ bq, const float* __restrict__ bk,
    const float* __restrict__ bv,
    ushort* __restrict__ Qb, ushort* __restrict__ Kb, ushort* __restrict__ Vt)
{
    const int mat = blockIdx.y;
    const ushort* __restrict__ Wt = (mat == 0) ? Wqt : (mat == 1) ? Wkt : Wvt;
    const float* __restrict__ bias = (mat == 0) ? bq : (mat == 1) ? bk : bv;
    const float bscale = (mat == 0) ? QSCALE : 1.0f;

    const int w = threadIdx.x >> 6, lane = threadIdx.x & 63;
    const int quad = lane >> 4, l16 = lane & 15;
    const int row0 = blockIdx.x * 64 + w * 16;

    floatx4 acc[16];
    #pragma unroll
    for (int i = 0; i < 16; ++i) acc[i] = (floatx4){0.f, 0.f, 0.f, 0.f};

    const float* __restrict__ xrow = x + (size_t)(row0 + l16) * EMB + quad * 8;

    #pragma unroll
    for (int ks = 0; ks < 8; ++ks) {
        const float4 xa0 = *(const float4*)(xrow + ks * 32);
        const float4 xa1 = *(const float4*)(xrow + ks * 32 + 4);
        ushort au[8] = {f2bf(xa0.x), f2bf(xa0.y), f2bf(xa0.z), f2bf(xa0.w),
                        f2bf(xa1.x), f2bf(xa1.y), f2bf(xa1.z), f2bf(xa1.w)};
        const short8 a = *(const short8*)au;
        #pragma unroll
        for (int i = 0; i < 16; ++i) {
            const short8 bf = *(const short8*)(Wt + (size_t)(i * 16 + l16) * EMB + ks * 32 + quad * 8);
            acc[i] = __builtin_amdgcn_mfma_f32_16x16x32_bf16(a, bf, acc[i], 0, 0, 0);
        }
    }

    const int gr0 = row0 + quad * 4;
    if (mat < 2) {
        ushort* __restrict__ dst = (mat == 0) ? Qb : Kb;
        #pragma unroll
        for (int i = 0; i < 16; ++i) {
            const int c = i * 16 + l16, h = c >> 5, d = c & (HD - 1);
            const float bb = bias[c] * bscale;
            #pragma unroll
            for (int r = 0; r < 4; ++r) {
                const int gr = gr0 + r, b = gr >> 10, n = gr & (SEQ - 1);
                dst[((size_t)(b * NH + h) * SEQ + n) * HD + d] = f2bf(acc[i][r] + bb);
            }
        }
    } else {
        const int b = gr0 >> 10, n0 = gr0 & (SEQ - 1);
        #pragma unroll
        for (int i = 0; i < 16; ++i) {
            const int c = i * 16 + l16, h = c >> 5, d = c & (HD - 1);
            const float bb = bias[c];
            ushort4 t4;
            t4.x = f2bf(acc[i][0] + bb); t4.y = f2bf(acc[i][1] + bb);
            t4.z = f2bf(acc[i][2] + bb); t4.w = f2bf(acc[i][3] + bb);
            *(ushort4*)(Vt + ((size_t)(b * NH + h) * HD + d) * SEQ + n0) = t4;
        }
    }
}

// ---------------------------------------------------------------------------
// Kernel 2: attention with MFMA-computed bias.
// Per 64-key iter:
//  phase A (coop, all 512 thr): Atile(f32, DMA'd) -> AbT bf16 [key][q*4+c]
//  phase B: per 16-key group: bias^T = 2 chained mfma(AbT, wa-diag, bah)
//           -> S^T = mfma(K, Q, C=bias^T) -> exp2 -> P^T -> in-register
//           cross-quad shuffle to B-layout -> PV mfma (ctx^T).
//  DMA for iter i+1 issued at top of phase B; barrier2's vmcnt(0) drains it.
// LDS = Atile 16.6 KB + AbT 11.3 KB = 27.9 KB -> 4 blocks/CU, grid = 1024
// blocks = exactly 4/CU (no tail). ctx^T stored [B,H,D,N] (coalesced).
// ---------------------------------------------------------------------------
__global__ __launch_bounds__(512, 8) void attn_kernel(
    const ushort* __restrict__ Qb, const ushort* __restrict__ Kb,
    const ushort* __restrict__ Vt, const float* __restrict__ adj,
    const float* __restrict__ Wa, const float* __restrict__ ba,
    float* __restrict__ cp, float* __restrict__ lsum)
{
    __shared__ float4  Atile[16][65];   // 16640 B (DMA fills cols 0..63)
    __shared__ ushort  AbT[64][88];     // 11264 B, bf16 [key][q*4+c], stride 176B
    const int tid = threadIdx.x, h = tid >> 6, lane = tid & 63;
    const int quad = lane >> 4, l16 = lane & 15;
    const int q0 = blockIdx.x * 16, b = blockIdx.y, z = blockIdx.z;
    const int bh = b * NH + h;
    const int kz = z * 512;

    const float LOG2E = 1.4426950408889634f;
    // diagonal wa B-frags (built once): B[k=(q',c)][n=q] = wa[c]*LOG2E iff q'==q
    ushort wab[4];
    #pragma unroll
    for (int c = 0; c < 4; ++c) wab[c] = f2bf(Wa[c * NH + h] * LOG2E);
    ushort wdv0[8] = {0,0,0,0,0,0,0,0}, wdv1[8] = {0,0,0,0,0,0,0,0};
    if (l16 == 2 * quad) {
        #pragma unroll
        for (int c = 0; c < 4; ++c) wdv0[c] = wab[c];
    } else if (l16 == 2 * quad + 1) {
        #pragma unroll
        for (int c = 0; c < 4; ++c) wdv0[4 + c] = wab[c];
    }
    if (l16 == 8 + 2 * quad) {
        #pragma unroll
        for (int c = 0; c < 4; ++c) wdv1[c] = wab[c];
    } else if (l16 == 9 + 2 * quad) {
        #pragma unroll
        for (int c = 0; c < 4; ++c) wdv1[4 + c] = wab[c];
    }
    const short8 wd0 = *(const short8*)wdv0;
    const short8 wd1 = *(const short8*)wdv1;
    const float bah = ba[h] * LOG2E;
    const floatx4 cinit = {bah, bah, bah, bah};

    // Q as B-operand: B[n=q=l16][k=d=quad*8+j]
    const short8 aq = *(const short8*)(Qb + ((size_t)bh * SEQ + q0 + l16) * HD + quad * 8);

    floatx4 o0 = {0.f, 0.f, 0.f, 0.f}, o1 = {0.f, 0.f, 0.f, 0.f};
    float lacc = 0.f;

    const float4* __restrict__ adjb = (const float4*)adj + (size_t)b * SEQ * SEQ;
    const float4* __restrict__ asrc0 = adjb + (size_t)(q0 + 2 * h)     * SEQ + kz + lane;
    const float4* __restrict__ asrc1 = adjb + (size_t)(q0 + 2 * h + 1) * SEQ + kz + lane;

    const ushort* __restrict__ Kbase = Kb + (size_t)bh * SEQ * HD + (size_t)l16 * HD + quad * 8;
    const ushort* __restrict__ Vb0 = Vt + ((size_t)bh * HD + l16) * SEQ + quad * 8;
    const ushort* __restrict__ Vb1 = Vt + ((size_t)bh * HD + 16 + l16) * SEQ + quad * 8;

    // shuffle sources for P^T C-layout -> B-layout (verified in r6)
    const int laneA = l16 | ((quad & 1) << 5);
    const int laneB = laneA + 16;
    const bool lowsel = quad < 2;

    // coop mapping: thread -> (q, keypair)
    const int cq = tid & 15, ckp = tid >> 4;   // ckp in [0,32)

    gload_lds16(asrc0, &Atile[2 * h][0]);
    gload_lds16(asrc1, &Atile[2 * h + 1][0]);
    __syncthreads();   // vmcnt(0) drain -> tile 0 resident

    for (int it = 0; it < 8; ++it) {
        // ---- phase A: convert adj tile to bf16 [key][q*4+c] ----
        {
            const float4 a0 = Atile[cq][2 * ckp];
            const float4 a1 = Atile[cq][2 * ckp + 1];
            uint2 w0, w1;
            w0.x = packtrunc(a0.x, a0.y); w0.y = packtrunc(a0.z, a0.w);
            w1.x = packtrunc(a1.x, a1.y); w1.y = packtrunc(a1.z, a1.w);
            *(uint2*)&AbT[2 * ckp][4 * cq]     = w0;
            *(uint2*)&AbT[2 * ckp + 1][4 * cq] = w1;
        }
        __syncthreads();   // AbT ready; Atile consumed

        if (it < 7) {      // async prefetch next adj tile into Atile
            gload_lds16(asrc0 + (it + 1) * 64, &Atile[2 * h][0]);
            gload_lds16(asrc1 + (it + 1) * 64, &Atile[2 * h + 1][0]);
        }
        const int key0 = kz + it * 64;

        // ---- phase B ----
        #pragma unroll
        for (int c = 0; c < 2; ++c) {
            const int kc = key0 + c * 32;
            float pA[4], pB[4];
            #pragma unroll
            for (int g = 0; g < 2; ++g) {
                const int krow = c * 32 + g * 16 + l16;   // AbT row (tile-rel key)
                const short8 ab1 = *(const short8*)&AbT[krow][quad * 8];
                const short8 ab2 = *(const short8*)&AbT[krow][32 + quad * 8];
                floatx4 bias = __builtin_amdgcn_mfma_f32_16x16x32_bf16(ab1, wd0, cinit, 0, 0, 0);
                bias = __builtin_amdgcn_mfma_f32_16x16x32_bf16(ab2, wd1, bias, 0, 0, 0);
                const short8 kA = *(const short8*)(Kbase + (size_t)(kc + g * 16) * HD);
                const floatx4 s = __builtin_amdgcn_mfma_f32_16x16x32_bf16(kA, aq, bias, 0, 0, 0);
                float* p = g ? pB : pA;
                #pragma unroll
                for (int r = 0; r < 4; ++r) {
                    p[r] = exp2f(s[r]);
                    lacc += p[r];
                }
            }
            // pack + cross-quad redistribution (r6-verified)
            const unsigned int d0 = packtrunc(pA[0], pA[1]);
            const unsigned int d1 = packtrunc(pA[2], pA[3]);
            const unsigned int d2 = packtrunc(pB[0], pB[1]);
            const unsigned int d3 = packtrunc(pB[2], pB[3]);
            const int t0A = __shfl((int)d0, laneA, 64);
            const int t2A = __shfl((int)d2, laneA, 64);
            const int t1A = __shfl((int)d1, laneA, 64);
            const int t3A = __shfl((int)d3, laneA, 64);
            const int t0B = __shfl((int)d0, laneB, 64);
            const int t2B = __shfl((int)d2, laneB, 64);
            const int t1B = __shfl((int)d1, laneB, 64);
            const int t3B = __shfl((int)d3, laneB, 64);
            int4 rr;
            rr.x = lowsel ? t0A : t2A;
            rr.y = lowsel ? t1A : t3A;
            rr.z = lowsel ? t0B : t2B;
            rr.w = lowsel ? t1B : t3B;
            const short8 bp = __builtin_bit_cast(short8, rr);   // B[n=q][k=key]

            const short8 va0 = *(const short8*)(Vb0 + kc);
            const short8 va1 = *(const short8*)(Vb1 + kc);
            o0 = __builtin_amdgcn_mfma_f32_16x16x32_bf16(va0, bp, o0, 0, 0, 0);
            o1 = __builtin_amdgcn_mfma_f32_16x16x32_bf16(va1, bp, o1, 0, 0, 0);
        }
        __syncthreads();   // AbT free for next coop; DMA drained (vmcnt 0)
    }

    // l per q=l16: sum across the 4 quads
    lacc += __shfl_xor(lacc, 16, 64);
    lacc += __shfl_xor(lacc, 32, 64);

    // ctx^T stored [z][B,H,D,N]: fully coalesced (16 consecutive n per quad)
    float* __restrict__ cpz = cp + (size_t)z * BATCH * NH * HD * SEQ;
    float* __restrict__ lsz = lsum + (size_t)z * BATCH * SEQ * NH;
    #pragma unroll
    for (int r = 0; r < 4; ++r) {
        cpz[((size_t)bh * HD + quad * 4 + r) * SEQ + q0 + l16]      = o0[r];
        cpz[((size_t)bh * HD + 16 + quad * 4 + r) * SEQ + q0 + l16] = o1[r];
    }
    if (lane < 16)
        lsz[((size_t)b * SEQ + q0 + lane) * NH + h] = lacc;
}

// ---------------------------------------------------------------------------
// Kernel 3: outproj as MFMA GEMM reading ctx^T [B,H,D,N] (coalesced dword
// loads: 16 consecutive n per lane-group). Combine z-splits, normalize,
// + bo + x residual.
// ---------------------------------------------------------------------------
__global__ __launch_bounds__(256) void outproj_gemm(
    const float* __restrict__ cp, const float* __restrict__ lsum,
    const ushort* __restrict__ Wot, const float* __restrict__ bo,
    const float* __restrict__ x, float* __restrict__ out)
{
    const int w = threadIdx.x >> 6, lane = threadIdx.x & 63;
    const int quad = lane >> 4, l16 = lane & 15;
    const int row0 = blockIdx.x * 64 + w * 16;
    const int arow = row0 + l16;
    const int b = arow >> 10, n = arow & (SEQ - 1);
    const float* __restrict__ cp1 = cp + (size_t)BATCH * NH * HD * SEQ;
    const float* __restrict__ l1  = lsum + (size_t)BATCH * SEQ * NH;

    floatx4 acc[16];
    #pragma unroll
    for (int i = 0; i < 16; ++i) acc[i] = (floatx4){0.f, 0.f, 0.f, 0.f};

    #pragma unroll
    for (int ks = 0; ks < 8; ++ks) {   // ks == head
        const float invl = 1.0f / (lsum[(size_t)arow * NH + ks] + l1[(size_t)arow * NH + ks]);
        const size_t dbase = ((size_t)(b * NH + ks) * HD + quad * 8) * SEQ + n;
        ushort au[8];
        #pragma unroll
        for (int j = 0; j < 8; ++j) {
            const float v = cp[dbase + (size_t)j * SEQ] + cp1[dbase + (size_t)j * SEQ];
            au[j] = f2bf(v * invl);
        }
        const short8 a = *(const short8*)au;
        #pragma unroll
        for (int i = 0; i < 16; ++i) {
            const short8 bfr = *(const short8*)(Wot + (size_t)(i * 16 + l16) * EMB + ks * 32 + quad * 8);
            acc[i] = __builtin_amdgcn_mfma_f32_16x16x32_bf16(a, bfr, acc[i], 0, 0, 0);
        }
    }

    const int gr0 = row0 + quad * 4;
    #pragma unroll
    for (int i = 0; i < 16; ++i) {
        const int c = i * 16 + l16;
        const float bov = bo[c];
        #pragma unroll
        for (int r = 0; r < 4; ++r) {
            const size_t idx = (size_t)(gr0 + r) * EMB + c;
            out[idx] = acc[i][r] + bov + x[idx];
        }
    }
}

extern "C" void kernel_launch(void* const* d_in, const int* in_sizes, int n_in,
                              void* d_out, int out_size, void* d_ws, size_t ws_size,
                              hipStream_t stream) {
    const float* x   = (const float*)d_in[0];
    const float* adj = (const float*)d_in[1];
    const float* Wq  = (const float*)d_in[2];
    const float* bq  = (const float*)d_in[3];
    const float* Wk  = (const float*)d_in[4];
    const float* bk  = (const float*)d_in[5];
    const float* Wv  = (const float*)d_in[6];
    const float* bv  = (const float*)d_in[7];
    const float* Wo  = (const float*)d_in[8];
    const float* bo  = (const float*)d_in[9];
    const float* Wa  = (const float*)d_in[10];
    const float* ba  = (const float*)d_in[11];

    const size_t per = (size_t)BATCH * NH * SEQ * HD;   // 2,097,152
    ushort* Qb  = (ushort*)d_ws;
    ushort* Kb  = Qb + per;
    ushort* Vt  = Kb + per;
    ushort* Wqt = Vt + per;
    ushort* Wkt = Wqt + EMB * EMB;
    ushort* Wvt = Wkt + EMB * EMB;
    ushort* Wot = Wvt + EMB * EMB;
    float*  cp  = (float*)(Wot + EMB * EMB);            // 2 x 8 MB fp32
    float*  ls  = cp + 2 * per;                         // 2 x 256 KB

    prep_kernel<<<256, 256, 0, stream>>>(Wq, Wk, Wv, Wo, Wqt, Wkt, Wvt, Wot);
    qkv_gemm<<<dim3(BATCH * SEQ / 64, 3), 256, 0, stream>>>(
        x, Wqt, Wkt, Wvt, bq, bk, bv, Qb, Kb, Vt);
    attn_kernel<<<dim3(SEQ / 16, BATCH, 2), 512, 0, stream>>>(
        Qb, Kb, Vt, adj, Wa, ba, cp, ls);
    outproj_gemm<<<BATCH * SEQ / 64, 256, 0, stream>>>(
        cp, ls, Wot, bo, x, (float*)d_out);
}